// Round 3
// baseline (139.882 us; speedup 1.0000x reference)
//
#include <hip/hip_runtime.h>
#include <math.h>

#define BATCH 4
#define NPTS  8000
#define NCH   256
#define GDIM  16            // 16^3 = 4096 cells, ~2 points/cell
#define NCELL (GDIM*GDIM*GDIM)
#define CELLH (1.0f/GDIM)

// ws layout (bytes):
//   counts  : [B][NCELL] int     @ 0        (65536)
//   cursors : [B][NCELL] int     @ 65536    (65536)   (zeroed with counts)
//   starts  : [B][NCELL] int     @ 131072   (65536)
//   psort   : [B][NPTS] float4   @ 196608   (512000)  (x,y,z, bitcast(orig j))
//   nbr     : [B][NPTS][2] int   @ 708608   (256000)
// total: 964608 bytes
#define WS_COUNTS  0
#define WS_CURSORS 65536
#define WS_STARTS  131072
#define WS_PSORT   196608
#define WS_NBR     708608

__device__ __forceinline__ int cell_clamp(float v) {
  int c = (int)(v * (float)GDIM);
  return c < 0 ? 0 : (c > GDIM - 1 ? GDIM - 1 : c);
}

__global__ void zero_kernel(int* __restrict__ p, int n) {
  const int i = blockIdx.x * 256 + threadIdx.x;
  if (i < n) p[i] = 0;
}

__global__ void count_kernel(const float* __restrict__ points, int* __restrict__ counts) {
  const int j = blockIdx.x * 256 + threadIdx.x;
  const int b = blockIdx.y;
  if (j >= NPTS) return;
  const float* p = points + ((size_t)b * NPTS + j) * 3;
  const int cid = (cell_clamp(p[2]) * GDIM + cell_clamp(p[1])) * GDIM + cell_clamp(p[0]);
  atomicAdd(&counts[b * NCELL + cid], 1);
}

// Exclusive scan of 4096 cell counts per batch; one block per batch.
__global__ __launch_bounds__(1024) void scan_kernel(const int* __restrict__ counts,
                                                    int* __restrict__ starts) {
  const int b = blockIdx.x;
  const int t = threadIdx.x;
  const int* c = counts + b * NCELL;
  int* s = starts + b * NCELL;
  const int v0 = c[t * 4 + 0], v1 = c[t * 4 + 1], v2 = c[t * 4 + 2], v3 = c[t * 4 + 3];
  const int sum = v0 + v1 + v2 + v3;
  __shared__ int sc[1024];
  sc[t] = sum;
  __syncthreads();
  for (int off = 1; off < 1024; off <<= 1) {
    int x = 0;
    if (t >= off) x = sc[t - off];
    __syncthreads();
    sc[t] += x;
    __syncthreads();
  }
  const int excl = sc[t] - sum;
  s[t * 4 + 0] = excl;
  s[t * 4 + 1] = excl + v0;
  s[t * 4 + 2] = excl + v0 + v1;
  s[t * 4 + 3] = excl + v0 + v1 + v2;
}

__global__ void scatter_kernel(const float* __restrict__ points,
                               const int* __restrict__ starts,
                               int* __restrict__ cursors,
                               float4* __restrict__ psort) {
  const int j = blockIdx.x * 256 + threadIdx.x;
  const int b = blockIdx.y;
  if (j >= NPTS) return;
  const float* p = points + ((size_t)b * NPTS + j) * 3;
  const float x = p[0], y = p[1], z = p[2];
  const int cid = (cell_clamp(z) * GDIM + cell_clamp(y)) * GDIM + cell_clamp(x);
  const int pos = starts[b * NCELL + cid] + atomicAdd(&cursors[b * NCELL + cid], 1);
  psort[b * NPTS + pos] = make_float4(x, y, z, __int_as_float(j));
}

// Per-query expanding-shell NN search. One thread per query.
// Tracks the top-2 of (d2, j) lexicographic (self is d2==0, captured at r=0).
// After finishing shell r, every unscanned point has true distance > r*CELLH,
// so computed d2 >= (r*CELLH)^2 - O(1e-6); break when b1 + 1e-5 <= (r*h)^2.
__global__ void search_kernel(const float* __restrict__ points,
                              const float4* __restrict__ psort,
                              const int* __restrict__ counts,
                              const int* __restrict__ starts,
                              int* __restrict__ nbr) {
  const int q = blockIdx.x * 256 + threadIdx.x;
  const int b = blockIdx.y;
  if (q >= NPTS) return;  // 8000 is NOT a multiple of 256 (R2 crash cause)
  const float* pb = points + (size_t)b * NPTS * 3;
  const float xi = pb[q * 3 + 0];
  const float yi = pb[q * 3 + 1];
  const float zi = pb[q * 3 + 2];
  const float sqi = xi * xi + yi * yi + zi * zi;  // same expr as reference path
  const int cx = cell_clamp(xi), cy = cell_clamp(yi), cz = cell_clamp(zi);
  const float4* ps = psort + (size_t)b * NPTS;
  const int* cnt = counts + b * NCELL;
  const int* st = starts + b * NCELL;

  float b0 = INFINITY, b1 = INFINITY;
  int j0 = -1, j1 = -1;

  for (int r = 0; r <= GDIM; ++r) {
    for (int dz = -r; dz <= r; ++dz) {
      const int z = cz + dz;
      if (z < 0 || z >= GDIM) continue;
      const bool zface = (dz == -r) || (dz == r);
      for (int dy = -r; dy <= r; ++dy) {
        const int y = cy + dy;
        if (y < 0 || y >= GDIM) continue;
        const bool face = zface || (dy == -r) || (dy == r);
        for (int dx = -r; dx <= r; ++dx) {
          if (!face && dx != -r && dx != r) continue;  // Chebyshev shell == r only
          const int x = cx + dx;
          if (x < 0 || x >= GDIM) continue;
          const int cid = (z * GDIM + y) * GDIM + x;
          const int cs = st[cid];
          const int n = cnt[cid];
          for (int p = 0; p < n; ++p) {
            const float4 P = ps[cs + p];
            const float dot = xi * P.x + yi * P.y + zi * P.z;
            const float sqj = P.x * P.x + P.y * P.y + P.z * P.z;
            const float d2 = (sqi + sqj) - 2.0f * dot;  // reference formula
            const int j = __float_as_int(P.w);
            const bool lt0 = (d2 < b0) || (d2 == b0 && j < j0);
            const bool lt1 = (d2 < b1) || (d2 == b1 && j < j1);
            if (lt0) {
              b1 = b0; j1 = j0; b0 = d2; j0 = j;
            } else if (lt1) {
              b1 = d2; j1 = j;
            }
          }
        }
      }
    }
    const float rb = (float)r * CELLH;
    if (b1 + 1e-5f <= rb * rb) break;
  }
  nbr[((size_t)b * NPTS + q) * 2 + 0] = j0;
  nbr[((size_t)b * NPTS + q) * 2 + 1] = j1;
}

// Gather + mean: one wave per query row, 64 lanes x float4 = 256 channels.
__global__ __launch_bounds__(256) void gather_kernel(const float* __restrict__ preds,
                                                     const int* __restrict__ nbr,
                                                     float* __restrict__ out) {
  const int wave = threadIdx.x >> 6;
  const int lane = threadIdx.x & 63;
  const int q = blockIdx.x * 4 + wave;
  const int b = blockIdx.y;
  const int a = nbr[((size_t)b * NPTS + q) * 2 + 0];
  const int c = nbr[((size_t)b * NPTS + q) * 2 + 1];
  const float* predb = preds + (size_t)b * NPTS * NCH;
  const float4 va = ((const float4*)(predb + (size_t)a * NCH))[lane];
  const float4 vc = ((const float4*)(predb + (size_t)c * NCH))[lane];
  float4 r;
  r.x = 0.5f * (va.x + vc.x);
  r.y = 0.5f * (va.y + vc.y);
  r.z = 0.5f * (va.z + vc.z);
  r.w = 0.5f * (va.w + vc.w);
  ((float4*)(out + ((size_t)b * NPTS + q) * NCH))[lane] = r;
}

extern "C" void kernel_launch(void* const* d_in, const int* in_sizes, int n_in,
                              void* d_out, int out_size, void* d_ws, size_t ws_size,
                              hipStream_t stream) {
  const float* points = (const float*)d_in[0];
  const float* preds = (const float*)d_in[1];
  // d_in[2] (k_vector) unused: reference hardcodes k = 2.
  float* out = (float*)d_out;

  char* ws = (char*)d_ws;
  int* counts = (int*)(ws + WS_COUNTS);
  int* cursors = (int*)(ws + WS_CURSORS);
  int* starts = (int*)(ws + WS_STARTS);
  float4* psort = (float4*)(ws + WS_PSORT);
  int* nbr = (int*)(ws + WS_NBR);

  const int nzero = 2 * BATCH * NCELL;  // counts + cursors
  zero_kernel<<<(nzero + 255) / 256, 256, 0, stream>>>(counts, nzero);

  dim3 pgrid((NPTS + 255) / 256, BATCH);
  count_kernel<<<pgrid, 256, 0, stream>>>(points, counts);
  scan_kernel<<<BATCH, 1024, 0, stream>>>(counts, starts);
  scatter_kernel<<<pgrid, 256, 0, stream>>>(points, starts, cursors, psort);
  search_kernel<<<pgrid, 256, 0, stream>>>(points, psort, counts, starts, nbr);
  gather_kernel<<<dim3(NPTS / 4, BATCH), 256, 0, stream>>>(preds, nbr, out);
}

// Round 4
// 128.260 us; speedup vs baseline: 1.0906x; 1.0906x over previous
//
#include <hip/hip_runtime.h>
#include <math.h>

#define BATCH 4
#define NPTS  8000
#define NCH   256
#define GDIM  16            // 16^3 = 4096 cells, ~2 points/cell
#define NCELL (GDIM*GDIM*GDIM)
#define CELLH (1.0f/GDIM)

// ws layout (bytes):
//   counts  : [B][NCELL] int     @ 0        (65536)
//   cursors : [B][NCELL] int     @ 65536    (65536)
//   starts  : [B][NCELL] int     @ 131072   (65536)   exclusive scan
//   psort   : [B][NPTS] float4   @ 196608   (512000)  (x,y,z, bitcast(orig j))
//   nbr     : [B][NPTS][2] int   @ 708608   (256000)
// total: 964608 bytes
#define WS_COUNTS  0
#define WS_CURSORS 65536
#define WS_STARTS  131072
#define WS_PSORT   196608
#define WS_NBR     708608

__device__ __forceinline__ int cell_clamp(float v) {
  int c = (int)(v * (float)GDIM);
  return c < 0 ? 0 : (c > GDIM - 1 ? GDIM - 1 : c);
}

__global__ void zero_kernel(int* __restrict__ p, int n) {
  const int i = blockIdx.x * 256 + threadIdx.x;
  if (i < n) p[i] = 0;
}

__global__ void count_kernel(const float* __restrict__ points, int* __restrict__ counts) {
  const int j = blockIdx.x * 256 + threadIdx.x;
  const int b = blockIdx.y;
  if (j >= NPTS) return;
  const float* p = points + ((size_t)b * NPTS + j) * 3;
  const int cid = (cell_clamp(p[2]) * GDIM + cell_clamp(p[1])) * GDIM + cell_clamp(p[0]);
  atomicAdd(&counts[b * NCELL + cid], 1);
}

// Exclusive scan of 4096 cell counts per batch; one block per batch.
__global__ __launch_bounds__(1024) void scan_kernel(const int* __restrict__ counts,
                                                    int* __restrict__ starts) {
  const int b = blockIdx.x;
  const int t = threadIdx.x;
  const int* c = counts + b * NCELL;
  int* s = starts + b * NCELL;
  const int v0 = c[t * 4 + 0], v1 = c[t * 4 + 1], v2 = c[t * 4 + 2], v3 = c[t * 4 + 3];
  const int sum = v0 + v1 + v2 + v3;
  __shared__ int sc[1024];
  sc[t] = sum;
  __syncthreads();
  for (int off = 1; off < 1024; off <<= 1) {
    int x = 0;
    if (t >= off) x = sc[t - off];
    __syncthreads();
    sc[t] += x;
    __syncthreads();
  }
  const int excl = sc[t] - sum;
  s[t * 4 + 0] = excl;
  s[t * 4 + 1] = excl + v0;
  s[t * 4 + 2] = excl + v0 + v1;
  s[t * 4 + 3] = excl + v0 + v1 + v2;
}

__global__ void scatter_kernel(const float* __restrict__ points,
                               const int* __restrict__ starts,
                               int* __restrict__ cursors,
                               float4* __restrict__ psort) {
  const int j = blockIdx.x * 256 + threadIdx.x;
  const int b = blockIdx.y;
  if (j >= NPTS) return;
  const float* p = points + ((size_t)b * NPTS + j) * 3;
  const float x = p[0], y = p[1], z = p[2];
  const int cid = (cell_clamp(z) * GDIM + cell_clamp(y)) * GDIM + cell_clamp(x);
  const int pos = starts[b * NCELL + cid] + atomicAdd(&cursors[b * NCELL + cid], 1);
  psort[b * NPTS + pos] = make_float4(x, y, z, __int_as_float(j));
}

// NN search in SORTED order: thread i handles the i-th point of psort, so a
// wave's 64 lanes are spatially adjacent -> uniform branches, L1-local loads.
// Fast path: 3x3x3 neighborhood as 9 contiguous sorted row-ranges (cells are
// contiguous along x in cid order); ranges from 18 INDEPENDENT starts[] loads.
// Fallback (rare, ~0.25%): generic Chebyshev shell walk from r=2.
// Top-2 of (d2, j) lexicographic; same d2 expression as the reference.
__global__ __launch_bounds__(64) void search_kernel(const float4* __restrict__ psort,
                                                    const int* __restrict__ counts,
                                                    const int* __restrict__ starts,
                                                    int* __restrict__ nbr) {
  const int i = blockIdx.x * 64 + threadIdx.x;  // sorted position
  const int b = blockIdx.y;
  if (i >= NPTS) return;
  const float4* ps = psort + (size_t)b * NPTS;
  const float4 Q = ps[i];
  const float xi = Q.x, yi = Q.y, zi = Q.z;
  const int qorig = __float_as_int(Q.w);
  const float sqi = xi * xi + yi * yi + zi * zi;  // same expr as reference
  const int cx = cell_clamp(xi), cy = cell_clamp(yi), cz = cell_clamp(zi);
  const int* cnt = counts + b * NCELL;
  const int* st = starts + b * NCELL;

  float b0 = INFINITY, b1 = INFINITY;
  int j0 = -1, j1 = -1;

  // ---- fast path: shells r<=1 as 9 row-ranges, statically indexed ----
  int rs[9], re[9];
#pragma unroll
  for (int kk = 0; kk < 9; ++kk) {
    const int dz = kk / 3 - 1, dy = kk % 3 - 1;
    const int z = cz + dz, y = cy + dy;
    const bool ok = ((unsigned)z < GDIM) && ((unsigned)y < GDIM);
    const int rowbase = (z * GDIM + y) * GDIM;
    const int x0 = cx > 0 ? cx - 1 : 0;
    const int x1 = cx < GDIM - 1 ? cx + 1 : GDIM - 1;
    const int clo = rowbase + x0, chi = rowbase + x1;
    rs[kk] = ok ? st[clo] : 0;
    re[kk] = ok ? ((chi + 1 < NCELL) ? st[chi + 1] : NPTS) : 0;
  }
#pragma unroll
  for (int kk = 0; kk < 9; ++kk) {
    for (int p = rs[kk]; p < re[kk]; ++p) {
      const float4 P = ps[p];
      const float dot = xi * P.x + yi * P.y + zi * P.z;
      const float sqj = P.x * P.x + P.y * P.y + P.z * P.z;
      const float d2 = (sqi + sqj) - 2.0f * dot;  // reference formula
      const int j = __float_as_int(P.w);
      const bool lt0 = (d2 < b0) || (d2 == b0 && j < j0);
      const bool lt1 = (d2 < b1) || (d2 == b1 && j < j1);
      if (lt0) {
        b1 = b0; j1 = j0; b0 = d2; j0 = j;
      } else if (lt1) {
        b1 = d2; j1 = j;
      }
    }
  }

  // ---- conservative stop bound after shells r<=1 ----
  if (!(b1 + 1e-5f <= CELLH * CELLH)) {
    // fallback: expand Chebyshev shells r=2.. (never rescans r<=1)
    for (int r = 2; r <= GDIM; ++r) {
      for (int dz = -r; dz <= r; ++dz) {
        const int z = cz + dz;
        if (z < 0 || z >= GDIM) continue;
        const bool zface = (dz == -r) || (dz == r);
        for (int dy = -r; dy <= r; ++dy) {
          const int y = cy + dy;
          if (y < 0 || y >= GDIM) continue;
          const bool face = zface || (dy == -r) || (dy == r);
          for (int dx = -r; dx <= r; ++dx) {
            if (!face && dx != -r && dx != r) continue;  // shell == r only
            const int x = cx + dx;
            if (x < 0 || x >= GDIM) continue;
            const int cid = (z * GDIM + y) * GDIM + x;
            const int cs = st[cid];
            const int n = cnt[cid];
            for (int p = 0; p < n; ++p) {
              const float4 P = ps[cs + p];
              const float dot = xi * P.x + yi * P.y + zi * P.z;
              const float sqj = P.x * P.x + P.y * P.y + P.z * P.z;
              const float d2 = (sqi + sqj) - 2.0f * dot;
              const int j = __float_as_int(P.w);
              const bool lt0 = (d2 < b0) || (d2 == b0 && j < j0);
              const bool lt1 = (d2 < b1) || (d2 == b1 && j < j1);
              if (lt0) {
                b1 = b0; j1 = j0; b0 = d2; j0 = j;
              } else if (lt1) {
                b1 = d2; j1 = j;
              }
            }
          }
        }
      }
      const float rb = (float)r * CELLH;
      if (b1 + 1e-5f <= rb * rb) break;
    }
  }

  nbr[((size_t)b * NPTS + qorig) * 2 + 0] = j0;
  nbr[((size_t)b * NPTS + qorig) * 2 + 1] = j1;
}

// Gather + mean: one wave per query row, 64 lanes x float4 = 256 channels.
__global__ __launch_bounds__(256) void gather_kernel(const float* __restrict__ preds,
                                                     const int* __restrict__ nbr,
                                                     float* __restrict__ out) {
  const int wave = threadIdx.x >> 6;
  const int lane = threadIdx.x & 63;
  const int q = blockIdx.x * 4 + wave;
  const int b = blockIdx.y;
  const int a = nbr[((size_t)b * NPTS + q) * 2 + 0];
  const int c = nbr[((size_t)b * NPTS + q) * 2 + 1];
  const float* predb = preds + (size_t)b * NPTS * NCH;
  const float4 va = ((const float4*)(predb + (size_t)a * NCH))[lane];
  const float4 vc = ((const float4*)(predb + (size_t)c * NCH))[lane];
  float4 r;
  r.x = 0.5f * (va.x + vc.x);
  r.y = 0.5f * (va.y + vc.y);
  r.z = 0.5f * (va.z + vc.z);
  r.w = 0.5f * (va.w + vc.w);
  ((float4*)(out + ((size_t)b * NPTS + q) * NCH))[lane] = r;
}

extern "C" void kernel_launch(void* const* d_in, const int* in_sizes, int n_in,
                              void* d_out, int out_size, void* d_ws, size_t ws_size,
                              hipStream_t stream) {
  const float* points = (const float*)d_in[0];
  const float* preds = (const float*)d_in[1];
  // d_in[2] (k_vector) unused: reference hardcodes k = 2.
  float* out = (float*)d_out;

  char* ws = (char*)d_ws;
  int* counts = (int*)(ws + WS_COUNTS);
  int* cursors = (int*)(ws + WS_CURSORS);
  int* starts = (int*)(ws + WS_STARTS);
  float4* psort = (float4*)(ws + WS_PSORT);
  int* nbr = (int*)(ws + WS_NBR);

  const int nzero = 2 * BATCH * NCELL;  // counts + cursors
  zero_kernel<<<(nzero + 255) / 256, 256, 0, stream>>>(counts, nzero);

  dim3 pgrid((NPTS + 255) / 256, BATCH);
  count_kernel<<<pgrid, 256, 0, stream>>>(points, counts);
  scan_kernel<<<BATCH, 1024, 0, stream>>>(counts, starts);
  scatter_kernel<<<pgrid, 256, 0, stream>>>(points, starts, cursors, psort);
  search_kernel<<<dim3((NPTS + 63) / 64, BATCH), 64, 0, stream>>>(psort, counts, starts, nbr);
  gather_kernel<<<dim3(NPTS / 4, BATCH), 256, 0, stream>>>(preds, nbr, out);
}

// Round 5
// 59.701 us; speedup vs baseline: 2.3430x; 2.1484x over previous
//
#include <hip/hip_runtime.h>
#include <math.h>

#define BATCH 4
#define NPTS  8000
#define NCH   256
#define GDIM  16            // 16^3 = 4096 cells, ~2 points/cell
#define NCELL (GDIM*GDIM*GDIM)
#define CELLH (1.0f/GDIM)
#define EPS   1e-5f

// ws layout (bytes):
//   counts  : [B][NCELL] int     @ 0        (65536)
//   cursors : [B][NCELL] int     @ 65536    (65536)
//   starts  : [B][NCELL] int     @ 131072   (65536)   exclusive scan
//   psort   : [B][NPTS] float4   @ 196608   (512000)  (x,y,z, bitcast(orig j))
//   nbr     : [B][NPTS][2] int   @ 708608   (256000)
#define WS_COUNTS  0
#define WS_CURSORS 65536
#define WS_STARTS  131072
#define WS_PSORT   196608
#define WS_NBR     708608

__device__ __forceinline__ int cell_clamp(float v) {
  int c = (int)(v * (float)GDIM);
  return c < 0 ? 0 : (c > GDIM - 1 ? GDIM - 1 : c);
}

__global__ void zero_kernel(int* __restrict__ p, int n) {
  const int i = blockIdx.x * 256 + threadIdx.x;
  if (i < n) p[i] = 0;
}

__global__ void count_kernel(const float* __restrict__ points, int* __restrict__ counts) {
  const int j = blockIdx.x * 256 + threadIdx.x;
  const int b = blockIdx.y;
  if (j >= NPTS) return;
  const float* p = points + ((size_t)b * NPTS + j) * 3;
  const int cid = (cell_clamp(p[2]) * GDIM + cell_clamp(p[1])) * GDIM + cell_clamp(p[0]);
  atomicAdd(&counts[b * NCELL + cid], 1);
}

// Exclusive scan of 4096 cell counts per batch; one block per batch.
__global__ __launch_bounds__(1024) void scan_kernel(const int* __restrict__ counts,
                                                    int* __restrict__ starts) {
  const int b = blockIdx.x;
  const int t = threadIdx.x;
  const int* c = counts + b * NCELL;
  int* s = starts + b * NCELL;
  const int v0 = c[t * 4 + 0], v1 = c[t * 4 + 1], v2 = c[t * 4 + 2], v3 = c[t * 4 + 3];
  const int sum = v0 + v1 + v2 + v3;
  __shared__ int sc[1024];
  sc[t] = sum;
  __syncthreads();
  for (int off = 1; off < 1024; off <<= 1) {
    int x = 0;
    if (t >= off) x = sc[t - off];
    __syncthreads();
    sc[t] += x;
    __syncthreads();
  }
  const int excl = sc[t] - sum;
  s[t * 4 + 0] = excl;
  s[t * 4 + 1] = excl + v0;
  s[t * 4 + 2] = excl + v0 + v1;
  s[t * 4 + 3] = excl + v0 + v1 + v2;
}

__global__ void scatter_kernel(const float* __restrict__ points,
                               const int* __restrict__ starts,
                               int* __restrict__ cursors,
                               float4* __restrict__ psort) {
  const int j = blockIdx.x * 256 + threadIdx.x;
  const int b = blockIdx.y;
  if (j >= NPTS) return;
  const float* p = points + ((size_t)b * NPTS + j) * 3;
  const float x = p[0], y = p[1], z = p[2];
  const int cid = (cell_clamp(z) * GDIM + cell_clamp(y)) * GDIM + cell_clamp(x);
  const int pos = starts[b * NCELL + cid] + atomicAdd(&cursors[b * NCELL + cid], 1);
  psort[b * NPTS + pos] = make_float4(x, y, z, __int_as_float(j));
}

// Candidate accumulation into per-lane top-2 of (max(d2,0), j) lexicographic
// -- exactly the reference's sort key: sqrt(max(d2,0)) monotone, stable
// top_k tie-break by lower index.
#define SCAN_RANGE(P0, P1)                                        \
  for (int p = (P0); p < (P1); ++p) {                             \
    const float4 P = ps[p];                                       \
    const float dot = xi * P.x + yi * P.y + zi * P.z;             \
    const float sqj = P.x * P.x + P.y * P.y + P.z * P.z;          \
    const float d2 = fmaxf((sqi + sqj) - 2.0f * dot, 0.0f);       \
    const int j = __float_as_int(P.w);                            \
    const bool lt0 = (d2 < b0) || (d2 == b0 && j < j0);           \
    const bool lt1 = (d2 < b1) || (d2 == b1 && j < j1);           \
    if (lt0) { b1 = b0; j1 = j0; b0 = d2; j0 = j; }               \
    else if (lt1) { b1 = d2; j1 = j; }                            \
  }

// Butterfly-merge step of two disjoint-set top-2 states (operates on mb*/mj*).
#define MERGE_XOR(MASK)                                                     \
  {                                                                         \
    const float ob0 = __shfl_xor(mb0, MASK);                                \
    const int oj0 = __shfl_xor(mj0, MASK);                                  \
    const float ob1 = __shfl_xor(mb1, MASK);                                \
    const int oj1 = __shfl_xor(mj1, MASK);                                  \
    const bool afirst = (mb0 < ob0) || (mb0 == ob0 && mj0 < oj0);           \
    const float w1 = afirst ? mb1 : ob1;                                    \
    const int wj1 = afirst ? mj1 : oj1;                                     \
    const float l0 = afirst ? ob0 : mb0;                                    \
    const int lj0 = afirst ? oj0 : mj0;                                     \
    mb0 = afirst ? mb0 : ob0;                                               \
    mj0 = afirst ? mj0 : oj0;                                               \
    const bool cs = (w1 < l0) || (w1 == l0 && wj1 < lj0);                   \
    mb1 = cs ? w1 : l0;                                                     \
    mj1 = cs ? wj1 : lj0;                                                   \
  }

// Sorted-order NN search, 8 lanes per query (256 threads = 32 queries).
// Everyone scans the full r<=2 box (25 rows x 5 cells, ~250 pts) as
// row-ranges from LDS-staged starts[]; conservative bound (2h)^2 then
// makes the shell fallback ~1-in-1e4 threads (extreme corner outliers),
// and the fallback itself is row-range LDS form too (no serial chains).
__global__ __launch_bounds__(256) void search_kernel(const float4* __restrict__ psort,
                                                     const int* __restrict__ starts,
                                                     int* __restrict__ nbr) {
  __shared__ int lst[NCELL + 1];
  const int t = threadIdx.x;
  const int b = blockIdx.y;
  const int* stg = starts + b * NCELL;
  for (int c = t; c < NCELL; c += 256) lst[c] = stg[c];
  if (t == 0) lst[NCELL] = NPTS;
  __syncthreads();

  const int ql = t >> 3;  // 0..31
  const int s = t & 7;    // candidate split lane
  const int i = blockIdx.x * 32 + ql;  // 250*32 == 8000 exact
  const float4* ps = psort + (size_t)b * NPTS;
  const float4 Q = ps[i];
  const float xi = Q.x, yi = Q.y, zi = Q.z;
  const int qorig = __float_as_int(Q.w);
  const float sqi = xi * xi + yi * yi + zi * zi;
  const int cx = cell_clamp(xi), cy = cell_clamp(yi), cz = cell_clamp(zi);
  const int x0c = cx > 1 ? cx - 2 : 0;
  const int x1c = cx < GDIM - 2 ? cx + 2 : GDIM - 1;

  float b0 = INFINITY, b1 = INFINITY;
  int j0 = -1, j1 = -1;

  // ---- r<=2 box: 25 rows, lane s takes rows s, s+8, s+16, s+24 ----
  int rs[4], re[4];
#pragma unroll
  for (int rr = 0; rr < 4; ++rr) {
    const int kk = s + rr * 8;
    int lo = 0, hi = 0;
    if (kk < 25) {
      const int z = cz + kk / 5 - 2;
      const int y = cy + kk % 5 - 2;
      if ((unsigned)z < GDIM && (unsigned)y < GDIM) {
        const int rowbase = (z * GDIM + y) * GDIM;
        lo = lst[rowbase + x0c];
        hi = lst[rowbase + x1c + 1];
      }
    }
    rs[rr] = lo;
    re[rr] = hi;
  }
#pragma unroll
  for (int rr = 0; rr < 4; ++rr) { SCAN_RANGE(rs[rr], re[rr]) }

  // merged stop-check copy (per-lane b0..j1 stay disjoint-set accumulators)
  float mb0 = b0, mb1 = b1;
  int mj0 = j0, mj1 = j1;
  MERGE_XOR(1) MERGE_XOR(2) MERGE_XOR(4)

  if (!(mb1 + EPS <= (2.0f * CELLH) * (2.0f * CELLH))) {
    // ---- rare fallback: expanding Chebyshev shells r>=3, row-range form ----
    for (int r = 3; r <= GDIM; ++r) {
      const int W = 2 * r + 1;
      for (int idx = s; idx < W * W; idx += 8) {
        const int dz = idx / W - r;
        const int dy = idx % W - r;
        const int z = cz + dz, y = cy + dy;
        if ((unsigned)z >= GDIM || (unsigned)y >= GDIM) continue;
        const int rowbase = (z * GDIM + y) * GDIM;
        if (dz == -r || dz == r || dy == -r || dy == r) {
          const int xl = cx > r ? cx - r : 0;
          const int xh = cx < GDIM - 1 - r ? cx + r : GDIM - 1;
          const int lo = lst[rowbase + xl], hi = lst[rowbase + xh + 1];
          SCAN_RANGE(lo, hi)
        } else {
          if (cx - r >= 0) {
            const int lo = lst[rowbase + cx - r], hi = lst[rowbase + cx - r + 1];
            SCAN_RANGE(lo, hi)
          }
          if (cx + r <= GDIM - 1) {
            const int lo = lst[rowbase + cx + r], hi = lst[rowbase + cx + r + 1];
            SCAN_RANGE(lo, hi)
          }
        }
      }
      mb0 = b0; mb1 = b1; mj0 = j0; mj1 = j1;
      MERGE_XOR(1) MERGE_XOR(2) MERGE_XOR(4)
      const float rb = (float)r * CELLH;
      if (mb1 + EPS <= rb * rb) break;
    }
  }

  if (s == 0) {
    nbr[((size_t)b * NPTS + qorig) * 2 + 0] = mj0;
    nbr[((size_t)b * NPTS + qorig) * 2 + 1] = mj1;
  }
}

// Gather + mean: one wave per query row, 64 lanes x float4 = 256 channels.
__global__ __launch_bounds__(256) void gather_kernel(const float* __restrict__ preds,
                                                     const int* __restrict__ nbr,
                                                     float* __restrict__ out) {
  const int wave = threadIdx.x >> 6;
  const int lane = threadIdx.x & 63;
  const int q = blockIdx.x * 4 + wave;
  const int b = blockIdx.y;
  const int a = nbr[((size_t)b * NPTS + q) * 2 + 0];
  const int c = nbr[((size_t)b * NPTS + q) * 2 + 1];
  const float* predb = preds + (size_t)b * NPTS * NCH;
  const float4 va = ((const float4*)(predb + (size_t)a * NCH))[lane];
  const float4 vc = ((const float4*)(predb + (size_t)c * NCH))[lane];
  float4 r;
  r.x = 0.5f * (va.x + vc.x);
  r.y = 0.5f * (va.y + vc.y);
  r.z = 0.5f * (va.z + vc.z);
  r.w = 0.5f * (va.w + vc.w);
  ((float4*)(out + ((size_t)b * NPTS + q) * NCH))[lane] = r;
}

extern "C" void kernel_launch(void* const* d_in, const int* in_sizes, int n_in,
                              void* d_out, int out_size, void* d_ws, size_t ws_size,
                              hipStream_t stream) {
  const float* points = (const float*)d_in[0];
  const float* preds = (const float*)d_in[1];
  // d_in[2] (k_vector) unused: reference hardcodes k = 2.
  float* out = (float*)d_out;

  char* ws = (char*)d_ws;
  int* counts = (int*)(ws + WS_COUNTS);
  int* cursors = (int*)(ws + WS_CURSORS);
  int* starts = (int*)(ws + WS_STARTS);
  float4* psort = (float4*)(ws + WS_PSORT);
  int* nbr = (int*)(ws + WS_NBR);

  const int nzero = 2 * BATCH * NCELL;  // counts + cursors
  zero_kernel<<<(nzero + 255) / 256, 256, 0, stream>>>(counts, nzero);

  dim3 pgrid((NPTS + 255) / 256, BATCH);
  count_kernel<<<pgrid, 256, 0, stream>>>(points, counts);
  scan_kernel<<<BATCH, 1024, 0, stream>>>(counts, starts);
  scatter_kernel<<<pgrid, 256, 0, stream>>>(points, starts, cursors, psort);
  search_kernel<<<dim3(NPTS / 32, BATCH), 256, 0, stream>>>(psort, starts, nbr);
  gather_kernel<<<dim3(NPTS / 4, BATCH), 256, 0, stream>>>(preds, nbr, out);
}

// Round 6
// 47.601 us; speedup vs baseline: 2.9387x; 1.2542x over previous
//
#include <hip/hip_runtime.h>
#include <math.h>

#define BATCH 4
#define NPTS  8000
#define NCH   256
#define GDIM  16            // 16^3 = 4096 cells, ~2 points/cell
#define NCELL (GDIM*GDIM*GDIM)
#define CELLH (1.0f/GDIM)
#define EPS   1e-5f

// ws layout (bytes):
//   starts : [B][NCELL] int   @ 0      (65536)   exclusive scan
//   psort  : [B][NPTS] float4 @ 65536  (512000)  (x,y,z, bitcast(orig j))
// total: 577536 bytes
#define WS_STARTS 0
#define WS_PSORT  65536

__device__ __forceinline__ int cell_clamp(float v) {
  int c = (int)(v * (float)GDIM);
  return c < 0 ? 0 : (c > GDIM - 1 ? GDIM - 1 : c);
}

// One block per batch: LDS histogram -> in-LDS exclusive scan -> global
// starts + scatter into psort via LDS cursors. Replaces 4 kernels.
__global__ __launch_bounds__(1024) void build_kernel(const float* __restrict__ points,
                                                     int* __restrict__ starts,
                                                     float4* __restrict__ psort) {
  __shared__ int lst[NCELL];
  __shared__ int sc[1024];
  const int t = threadIdx.x;
  const int b = blockIdx.x;
  for (int c = t; c < NCELL; c += 1024) lst[c] = 0;
  __syncthreads();

  const float* pb = points + (size_t)b * NPTS * 3;
  float px[8], py[8], pz[8];
  int pc[8];
#pragma unroll
  for (int k = 0; k < 8; ++k) {
    const int j = t + k * 1024;
    pc[k] = -1;
    if (j < NPTS) {
      px[k] = pb[j * 3 + 0];
      py[k] = pb[j * 3 + 1];
      pz[k] = pb[j * 3 + 2];
      pc[k] = (cell_clamp(pz[k]) * GDIM + cell_clamp(py[k])) * GDIM + cell_clamp(px[k]);
      atomicAdd(&lst[pc[k]], 1);
    }
  }
  __syncthreads();

  // exclusive scan of 4096 counts (4 per thread)
  const int v0 = lst[t * 4 + 0], v1 = lst[t * 4 + 1], v2 = lst[t * 4 + 2], v3 = lst[t * 4 + 3];
  const int sum = v0 + v1 + v2 + v3;
  sc[t] = sum;
  __syncthreads();
  for (int off = 1; off < 1024; off <<= 1) {
    int x = 0;
    if (t >= off) x = sc[t - off];
    __syncthreads();
    sc[t] += x;
    __syncthreads();
  }
  const int excl = sc[t] - sum;
  const int s0 = excl, s1 = excl + v0, s2 = excl + v0 + v1, s3 = excl + v0 + v1 + v2;
  int* stg = starts + b * NCELL;
  stg[t * 4 + 0] = s0;
  stg[t * 4 + 1] = s1;
  stg[t * 4 + 2] = s2;
  stg[t * 4 + 3] = s3;
  // each thread overwrites only its own 4 cells; no other thread reads lst here
  lst[t * 4 + 0] = s0;
  lst[t * 4 + 1] = s1;
  lst[t * 4 + 2] = s2;
  lst[t * 4 + 3] = s3;
  __syncthreads();

  // scatter (LDS cursors)
  float4* psb = psort + (size_t)b * NPTS;
#pragma unroll
  for (int k = 0; k < 8; ++k) {
    if (pc[k] >= 0) {
      const int pos = atomicAdd(&lst[pc[k]], 1);
      psb[pos] = make_float4(px[k], py[k], pz[k], __int_as_float(t + k * 1024));
    }
  }
}

// Candidate accumulation into per-lane top-2 of (max(d2,0), j) lexicographic
// -- exactly the reference's sort key: sqrt(max(d2,0)) monotone, stable
// top_k tie-break by lower index.
#define SCAN_RANGE(P0, P1)                                        \
  for (int p = (P0); p < (P1); ++p) {                             \
    const float4 P = ps[p];                                       \
    const float dot = xi * P.x + yi * P.y + zi * P.z;             \
    const float sqj = P.x * P.x + P.y * P.y + P.z * P.z;          \
    const float d2 = fmaxf((sqi + sqj) - 2.0f * dot, 0.0f);       \
    const int j = __float_as_int(P.w);                            \
    const bool lt0 = (d2 < b0) || (d2 == b0 && j < j0);           \
    const bool lt1 = (d2 < b1) || (d2 == b1 && j < j1);           \
    if (lt0) { b1 = b0; j1 = j0; b0 = d2; j0 = j; }               \
    else if (lt1) { b1 = d2; j1 = j; }                            \
  }

// Butterfly-merge step of two disjoint-set top-2 states (operates on mb*/mj*).
#define MERGE_XOR(MASK)                                                     \
  {                                                                         \
    const float ob0 = __shfl_xor(mb0, MASK);                                \
    const int oj0 = __shfl_xor(mj0, MASK);                                  \
    const float ob1 = __shfl_xor(mb1, MASK);                                \
    const int oj1 = __shfl_xor(mj1, MASK);                                  \
    const bool afirst = (mb0 < ob0) || (mb0 == ob0 && mj0 < oj0);           \
    const float w1 = afirst ? mb1 : ob1;                                    \
    const int wj1 = afirst ? mj1 : oj1;                                     \
    const float l0 = afirst ? ob0 : mb0;                                    \
    const int lj0 = afirst ? oj0 : mj0;                                     \
    mb0 = afirst ? mb0 : ob0;                                               \
    mj0 = afirst ? mj0 : oj0;                                               \
    const bool cs = (w1 < l0) || (w1 == l0 && wj1 < lj0);                   \
    mb1 = cs ? w1 : l0;                                                     \
    mj1 = cs ? wj1 : lj0;                                                   \
  }

// Fused NN search + gather/mean. 256 threads = 32 sorted-order queries x
// 8 candidate-split lanes. Search: full r<=2 box (25 rows x 5 cells) as
// row-ranges from LDS-staged starts[]; conservative (2h)^2 stop bound makes
// the shell fallback ~1e-4 rare. Epilogue: block broadcasts (j0,j1,qorig)
// via LDS, then 4 waves gather preds rows (64 lanes x float4 = 256 ch).
__global__ __launch_bounds__(256) void search_gather_kernel(
    const float4* __restrict__ psort, const int* __restrict__ starts,
    const float* __restrict__ preds, float* __restrict__ out) {
  __shared__ int lst[NCELL + 1];
  __shared__ int snbr[32][3];  // j0, j1, qorig
  const int t = threadIdx.x;
  const int b = blockIdx.y;
  const int* stg = starts + b * NCELL;
  for (int c = t; c < NCELL; c += 256) lst[c] = stg[c];
  if (t == 0) lst[NCELL] = NPTS;
  __syncthreads();

  const int ql = t >> 3;  // 0..31
  const int s = t & 7;    // candidate split lane
  const int i = blockIdx.x * 32 + ql;  // 250*32 == 8000 exact
  const float4* ps = psort + (size_t)b * NPTS;
  const float4 Q = ps[i];
  const float xi = Q.x, yi = Q.y, zi = Q.z;
  const int qorig = __float_as_int(Q.w);
  const float sqi = xi * xi + yi * yi + zi * zi;  // same expr as reference
  const int cx = cell_clamp(xi), cy = cell_clamp(yi), cz = cell_clamp(zi);
  const int x0c = cx > 1 ? cx - 2 : 0;
  const int x1c = cx < GDIM - 2 ? cx + 2 : GDIM - 1;

  float b0 = INFINITY, b1 = INFINITY;
  int j0 = -1, j1 = -1;

  // ---- r<=2 box: 25 rows, lane s takes rows s, s+8, s+16, s+24 ----
  int rs[4], re[4];
#pragma unroll
  for (int rr = 0; rr < 4; ++rr) {
    const int kk = s + rr * 8;
    int lo = 0, hi = 0;
    if (kk < 25) {
      const int z = cz + kk / 5 - 2;
      const int y = cy + kk % 5 - 2;
      if ((unsigned)z < GDIM && (unsigned)y < GDIM) {
        const int rowbase = (z * GDIM + y) * GDIM;
        lo = lst[rowbase + x0c];
        hi = lst[rowbase + x1c + 1];
      }
    }
    rs[rr] = lo;
    re[rr] = hi;
  }
#pragma unroll
  for (int rr = 0; rr < 4; ++rr) { SCAN_RANGE(rs[rr], re[rr]) }

  // merged stop-check copy (per-lane b0..j1 stay disjoint-set accumulators)
  float mb0 = b0, mb1 = b1;
  int mj0 = j0, mj1 = j1;
  MERGE_XOR(1) MERGE_XOR(2) MERGE_XOR(4)

  if (!(mb1 + EPS <= (2.0f * CELLH) * (2.0f * CELLH))) {
    // ---- rare fallback: expanding Chebyshev shells r>=3, row-range form ----
    for (int r = 3; r <= GDIM; ++r) {
      const int W = 2 * r + 1;
      for (int idx = s; idx < W * W; idx += 8) {
        const int dz = idx / W - r;
        const int dy = idx % W - r;
        const int z = cz + dz, y = cy + dy;
        if ((unsigned)z >= GDIM || (unsigned)y >= GDIM) continue;
        const int rowbase = (z * GDIM + y) * GDIM;
        if (dz == -r || dz == r || dy == -r || dy == r) {
          const int xl = cx > r ? cx - r : 0;
          const int xh = cx < GDIM - 1 - r ? cx + r : GDIM - 1;
          const int lo = lst[rowbase + xl], hi = lst[rowbase + xh + 1];
          SCAN_RANGE(lo, hi)
        } else {
          if (cx - r >= 0) {
            const int lo = lst[rowbase + cx - r], hi = lst[rowbase + cx - r + 1];
            SCAN_RANGE(lo, hi)
          }
          if (cx + r <= GDIM - 1) {
            const int lo = lst[rowbase + cx + r], hi = lst[rowbase + cx + r + 1];
            SCAN_RANGE(lo, hi)
          }
        }
      }
      mb0 = b0; mb1 = b1; mj0 = j0; mj1 = j1;
      MERGE_XOR(1) MERGE_XOR(2) MERGE_XOR(4)
      const float rb = (float)r * CELLH;
      if (mb1 + EPS <= rb * rb) break;
    }
  }

  if (s == 0) {
    snbr[ql][0] = mj0;
    snbr[ql][1] = mj1;
    snbr[ql][2] = qorig;
  }
  __syncthreads();

  // ---- gather + mean epilogue: wave w handles queries w, w+4, ... ----
  const int wave = t >> 6;
  const int lane = t & 63;
  const float* predb = preds + (size_t)b * NPTS * NCH;
  float* outb = out + (size_t)b * NPTS * NCH;
  for (int q = wave; q < 32; q += 4) {
    const int a = snbr[q][0];
    const int c = snbr[q][1];
    const int qo = snbr[q][2];
    const float4 va = ((const float4*)(predb + (size_t)a * NCH))[lane];
    const float4 vc = ((const float4*)(predb + (size_t)c * NCH))[lane];
    float4 r;
    r.x = 0.5f * (va.x + vc.x);
    r.y = 0.5f * (va.y + vc.y);
    r.z = 0.5f * (va.z + vc.z);
    r.w = 0.5f * (va.w + vc.w);
    ((float4*)(outb + (size_t)qo * NCH))[lane] = r;
  }
}

extern "C" void kernel_launch(void* const* d_in, const int* in_sizes, int n_in,
                              void* d_out, int out_size, void* d_ws, size_t ws_size,
                              hipStream_t stream) {
  const float* points = (const float*)d_in[0];
  const float* preds = (const float*)d_in[1];
  // d_in[2] (k_vector) unused: reference hardcodes k = 2.
  float* out = (float*)d_out;

  char* ws = (char*)d_ws;
  int* starts = (int*)(ws + WS_STARTS);
  float4* psort = (float4*)(ws + WS_PSORT);

  build_kernel<<<BATCH, 1024, 0, stream>>>(points, starts, psort);
  search_gather_kernel<<<dim3(NPTS / 32, BATCH), 256, 0, stream>>>(psort, starts, preds, out);
}

// Round 7
// 40.207 us; speedup vs baseline: 3.4790x; 1.1839x over previous
//
#include <hip/hip_runtime.h>
#include <math.h>

#define BATCH 4
#define NPTS  8000
#define NCH   256
#define GDIM  16            // 16^3 = 4096 cells, ~2 points/cell
#define NCELL (GDIM*GDIM*GDIM)
#define CELLH (1.0f/GDIM)
#define EPS   1e-5f

// ws layout (bytes):
//   starts : [B][NCELL+16] int @ 0      (65792)  exclusive scan + sentinel
//   psort  : [B][NPTS] float4  @ 65792  (512000) (x,y,z, bitcast(orig j))
// total: 577792 bytes
#define STRIDE_ST (NCELL + 16)
#define WS_STARTS 0
#define WS_PSORT  65792

__device__ __forceinline__ int cell_clamp(float v) {
  int c = (int)(v * (float)GDIM);
  return c < 0 ? 0 : (c > GDIM - 1 ? GDIM - 1 : c);
}

// One block per batch: LDS histogram -> in-LDS exclusive scan -> global
// starts (+ sentinel) + scatter into psort via LDS cursors.
__global__ __launch_bounds__(1024) void build_kernel(const float* __restrict__ points,
                                                     int* __restrict__ starts,
                                                     float4* __restrict__ psort) {
  __shared__ int lst[NCELL];
  __shared__ int sc[1024];
  const int t = threadIdx.x;
  const int b = blockIdx.x;
  for (int c = t; c < NCELL; c += 1024) lst[c] = 0;
  __syncthreads();

  const float* pb = points + (size_t)b * NPTS * 3;
  float px[8], py[8], pz[8];
  int pc[8];
#pragma unroll
  for (int k = 0; k < 8; ++k) {
    const int j = t + k * 1024;
    pc[k] = -1;
    if (j < NPTS) {
      px[k] = pb[j * 3 + 0];
      py[k] = pb[j * 3 + 1];
      pz[k] = pb[j * 3 + 2];
      pc[k] = (cell_clamp(pz[k]) * GDIM + cell_clamp(py[k])) * GDIM + cell_clamp(px[k]);
      atomicAdd(&lst[pc[k]], 1);
    }
  }
  __syncthreads();

  // exclusive scan of 4096 counts (4 per thread)
  const int v0 = lst[t * 4 + 0], v1 = lst[t * 4 + 1], v2 = lst[t * 4 + 2], v3 = lst[t * 4 + 3];
  const int sum = v0 + v1 + v2 + v3;
  sc[t] = sum;
  __syncthreads();
  for (int off = 1; off < 1024; off <<= 1) {
    int x = 0;
    if (t >= off) x = sc[t - off];
    __syncthreads();
    sc[t] += x;
    __syncthreads();
  }
  const int excl = sc[t] - sum;
  const int s0 = excl, s1 = excl + v0, s2 = excl + v0 + v1, s3 = excl + v0 + v1 + v2;
  int* stg = starts + b * STRIDE_ST;
  stg[t * 4 + 0] = s0;
  stg[t * 4 + 1] = s1;
  stg[t * 4 + 2] = s2;
  stg[t * 4 + 3] = s3;
  if (t == 0) stg[NCELL] = NPTS;  // sentinel: end of last cell
  // each thread overwrites only its own 4 cells; no other thread reads lst here
  lst[t * 4 + 0] = s0;
  lst[t * 4 + 1] = s1;
  lst[t * 4 + 2] = s2;
  lst[t * 4 + 3] = s3;
  __syncthreads();

  // scatter (LDS cursors)
  float4* psb = psort + (size_t)b * NPTS;
#pragma unroll
  for (int k = 0; k < 8; ++k) {
    if (pc[k] >= 0) {
      const int pos = atomicAdd(&lst[pc[k]], 1);
      psb[pos] = make_float4(px[k], py[k], pz[k], __int_as_float(t + k * 1024));
    }
  }
}

// Candidate accumulation into per-lane top-2 of (max(d2,0), j) lexicographic
// -- exactly the reference's sort key: sqrt(max(d2,0)) monotone, stable
// top_k tie-break by lower index.
#define SCAN_RANGE(P0, P1)                                        \
  for (int p = (P0); p < (P1); ++p) {                             \
    const float4 P = ps[p];                                       \
    const float dot = xi * P.x + yi * P.y + zi * P.z;             \
    const float sqj = P.x * P.x + P.y * P.y + P.z * P.z;          \
    const float d2 = fmaxf((sqi + sqj) - 2.0f * dot, 0.0f);       \
    const int j = __float_as_int(P.w);                            \
    const bool lt0 = (d2 < b0) || (d2 == b0 && j < j0);           \
    const bool lt1 = (d2 < b1) || (d2 == b1 && j < j1);           \
    if (lt0) { b1 = b0; j1 = j0; b0 = d2; j0 = j; }               \
    else if (lt1) { b1 = d2; j1 = j; }                            \
  }

// Butterfly-merge step of two disjoint-set top-2 states (operates on mb*/mj*).
#define MERGE_XOR(MASK)                                                     \
  {                                                                         \
    const float ob0 = __shfl_xor(mb0, MASK);                                \
    const int oj0 = __shfl_xor(mj0, MASK);                                  \
    const float ob1 = __shfl_xor(mb1, MASK);                                \
    const int oj1 = __shfl_xor(mj1, MASK);                                  \
    const bool afirst = (mb0 < ob0) || (mb0 == ob0 && mj0 < oj0);           \
    const float w1 = afirst ? mb1 : ob1;                                    \
    const int wj1 = afirst ? mj1 : oj1;                                     \
    const float l0 = afirst ? ob0 : mb0;                                    \
    const int lj0 = afirst ? oj0 : mj0;                                     \
    mb0 = afirst ? mb0 : ob0;                                               \
    mj0 = afirst ? mj0 : oj0;                                               \
    const bool cs = (w1 < l0) || (w1 == l0 && wj1 < lj0);                   \
    mb1 = cs ? w1 : l0;                                                     \
    mj1 = cs ? wj1 : lj0;                                                   \
  }

// Fused NN search + gather/mean. 256 threads = 16 sorted-order queries x
// 16 candidate-split lanes (500 blocks/batch -> ~full occupancy; forced
// <=64 VGPR via launch_bounds). starts[] read straight from L2 (16KB/batch,
// hot) -- no LDS staging, no startup barrier. Full r<=2 box (25 rows x
// 5 cells) as row-ranges; conservative (2h)^2 stop bound makes the shell
// fallback ~1e-4 rare. Epilogue: 4 waves x 4 queries, unrolled gather.
__global__ __launch_bounds__(256, 8) void search_gather_kernel(
    const float4* __restrict__ psort, const int* __restrict__ starts,
    const float* __restrict__ preds, float* __restrict__ out) {
  __shared__ int snbr[16][3];  // j0, j1, qorig
  const int t = threadIdx.x;
  const int b = blockIdx.y;
  const int* stg = starts + b * STRIDE_ST;

  const int ql = t >> 4;  // 0..15
  const int s = t & 15;   // candidate split lane
  const int i = blockIdx.x * 16 + ql;  // 500*16 == 8000 exact
  const float4* ps = psort + (size_t)b * NPTS;
  const float4 Q = ps[i];
  const float xi = Q.x, yi = Q.y, zi = Q.z;
  const int qorig = __float_as_int(Q.w);
  const float sqi = xi * xi + yi * yi + zi * zi;  // same expr as reference
  const int cx = cell_clamp(xi), cy = cell_clamp(yi), cz = cell_clamp(zi);
  const int x0c = cx > 1 ? cx - 2 : 0;
  const int x1c = cx < GDIM - 2 ? cx + 2 : GDIM - 1;

  float b0 = INFINITY, b1 = INFINITY;
  int j0 = -1, j1 = -1;

  // ---- r<=2 box: 25 rows, lane s takes rows s and s+16 ----
  int rs[2], re[2];
#pragma unroll
  for (int rr = 0; rr < 2; ++rr) {
    const int kk = s + rr * 16;
    int lo = 0, hi = 0;
    if (kk < 25) {
      const int z = cz + kk / 5 - 2;
      const int y = cy + kk % 5 - 2;
      if ((unsigned)z < GDIM && (unsigned)y < GDIM) {
        const int rowbase = (z * GDIM + y) * GDIM;
        lo = stg[rowbase + x0c];
        hi = stg[rowbase + x1c + 1];  // sentinel covers rowbase+x1c+1 == NCELL
      }
    }
    rs[rr] = lo;
    re[rr] = hi;
  }
#pragma unroll
  for (int rr = 0; rr < 2; ++rr) { SCAN_RANGE(rs[rr], re[rr]) }

  // merged stop-check copy (per-lane b0..j1 stay disjoint-set accumulators)
  float mb0 = b0, mb1 = b1;
  int mj0 = j0, mj1 = j1;
  MERGE_XOR(1) MERGE_XOR(2) MERGE_XOR(4) MERGE_XOR(8)

  if (!(mb1 + EPS <= (2.0f * CELLH) * (2.0f * CELLH))) {
    // ---- rare fallback: expanding Chebyshev shells r>=3, row-range form ----
    for (int r = 3; r <= GDIM; ++r) {
      const int W = 2 * r + 1;
      for (int idx = s; idx < W * W; idx += 16) {
        const int dz = idx / W - r;
        const int dy = idx % W - r;
        const int z = cz + dz, y = cy + dy;
        if ((unsigned)z >= GDIM || (unsigned)y >= GDIM) continue;
        const int rowbase = (z * GDIM + y) * GDIM;
        if (dz == -r || dz == r || dy == -r || dy == r) {
          const int xl = cx > r ? cx - r : 0;
          const int xh = cx < GDIM - 1 - r ? cx + r : GDIM - 1;
          const int lo = stg[rowbase + xl], hi = stg[rowbase + xh + 1];
          SCAN_RANGE(lo, hi)
        } else {
          if (cx - r >= 0) {
            const int lo = stg[rowbase + cx - r], hi = stg[rowbase + cx - r + 1];
            SCAN_RANGE(lo, hi)
          }
          if (cx + r <= GDIM - 1) {
            const int lo = stg[rowbase + cx + r], hi = stg[rowbase + cx + r + 1];
            SCAN_RANGE(lo, hi)
          }
        }
      }
      mb0 = b0; mb1 = b1; mj0 = j0; mj1 = j1;
      MERGE_XOR(1) MERGE_XOR(2) MERGE_XOR(4) MERGE_XOR(8)
      const float rb = (float)r * CELLH;
      if (mb1 + EPS <= rb * rb) break;
    }
  }

  if (s == 0) {
    snbr[ql][0] = mj0;
    snbr[ql][1] = mj1;
    snbr[ql][2] = qorig;
  }
  __syncthreads();

  // ---- gather + mean epilogue: wave w handles queries 4w..4w+3 ----
  const int wave = t >> 6;
  const int lane = t & 63;
  const float* predb = preds + (size_t)b * NPTS * NCH;
  float* outb = out + (size_t)b * NPTS * NCH;
#pragma unroll
  for (int k = 0; k < 4; ++k) {
    const int q = wave * 4 + k;
    const int a = snbr[q][0];
    const int c = snbr[q][1];
    const int qo = snbr[q][2];
    const float4 va = ((const float4*)(predb + (size_t)a * NCH))[lane];
    const float4 vc = ((const float4*)(predb + (size_t)c * NCH))[lane];
    float4 r;
    r.x = 0.5f * (va.x + vc.x);
    r.y = 0.5f * (va.y + vc.y);
    r.z = 0.5f * (va.z + vc.z);
    r.w = 0.5f * (va.w + vc.w);
    ((float4*)(outb + (size_t)qo * NCH))[lane] = r;
  }
}

extern "C" void kernel_launch(void* const* d_in, const int* in_sizes, int n_in,
                              void* d_out, int out_size, void* d_ws, size_t ws_size,
                              hipStream_t stream) {
  const float* points = (const float*)d_in[0];
  const float* preds = (const float*)d_in[1];
  // d_in[2] (k_vector) unused: reference hardcodes k = 2.
  float* out = (float*)d_out;

  char* ws = (char*)d_ws;
  int* starts = (int*)(ws + WS_STARTS);
  float4* psort = (float4*)(ws + WS_PSORT);

  build_kernel<<<BATCH, 1024, 0, stream>>>(points, starts, psort);
  search_gather_kernel<<<dim3(NPTS / 16, BATCH), 256, 0, stream>>>(psort, starts, preds, out);
}

// Round 8
// 36.445 us; speedup vs baseline: 3.8382x; 1.1032x over previous
//
#include <hip/hip_runtime.h>
#include <math.h>

#define BATCH 4
#define NPTS  8000
#define NCH   256
#define GDIM  20            // 20^3 = 8000 cells, ~1 point/cell
#define NCELL (GDIM*GDIM*GDIM)
#define CELLH (1.0f/GDIM)
#define EPS   1e-5f

// ws layout (bytes):
//   starts : [B][NCELL+16] int @ 0       (4*8016*4 = 128256)  excl scan + sentinel
//   psort  : [B][NPTS] float4  @ 131072  (512000)             (x,y,z, bitcast(orig j))
// total: 643072 bytes
#define STRIDE_ST (NCELL + 16)
#define WS_STARTS 0
#define WS_PSORT  131072

__device__ __forceinline__ int cell_clamp(float v) {
  int c = (int)(v * (float)GDIM);
  return c < 0 ? 0 : (c > GDIM - 1 ? GDIM - 1 : c);
}

// One block per batch: LDS histogram -> shuffle-scan (3 barriers) -> global
// starts (+ sentinel) + scatter into psort via LDS cursors.
// Cells per thread: threads 0..999 own 8 cells each (1000*8 == NCELL).
__global__ __launch_bounds__(1024) void build_kernel(const float* __restrict__ points,
                                                     int* __restrict__ starts,
                                                     float4* __restrict__ psort) {
  __shared__ int lst[NCELL];
  __shared__ int wtot[16];
  const int t = threadIdx.x;
  const int b = blockIdx.x;
  if (t < 1000) {
#pragma unroll
    for (int k = 0; k < 8; ++k) lst[t * 8 + k] = 0;
  }
  __syncthreads();

  const float* pb = points + (size_t)b * NPTS * 3;
  float px[8], py[8], pz[8];
  int pc[8];
#pragma unroll
  for (int k = 0; k < 8; ++k) {
    const int j = t + k * 1024;
    pc[k] = -1;
    if (j < NPTS) {
      px[k] = pb[j * 3 + 0];
      py[k] = pb[j * 3 + 1];
      pz[k] = pb[j * 3 + 2];
      pc[k] = (cell_clamp(pz[k]) * GDIM + cell_clamp(py[k])) * GDIM + cell_clamp(px[k]);
      atomicAdd(&lst[pc[k]], 1);
    }
  }
  __syncthreads();

  // per-thread sum of its 8 cells
  int v[8];
  int sum = 0;
  if (t < 1000) {
#pragma unroll
    for (int k = 0; k < 8; ++k) {
      v[k] = lst[t * 8 + k];
      sum += v[k];
    }
  }
  // wave-level inclusive scan of thread sums
  const int lane = t & 63, wv = t >> 6;
  int incl = sum;
#pragma unroll
  for (int d = 1; d < 64; d <<= 1) {
    const int u = __shfl_up(incl, d);
    if (lane >= d) incl += u;
  }
  if (lane == 63) wtot[wv] = incl;
  __syncthreads();
  if (wv == 0) {
    int x = (lane < 16) ? wtot[lane] : 0;
#pragma unroll
    for (int d = 1; d < 16; d <<= 1) {
      const int u = __shfl_up(x, d);
      if (lane >= d) x += u;
    }
    if (lane < 16) wtot[lane] = x;
  }
  __syncthreads();
  const int base = incl - sum + (wv ? wtot[wv - 1] : 0);

  int* stg = starts + b * STRIDE_ST;
  if (t < 1000) {
    int run = base;
#pragma unroll
    for (int k = 0; k < 8; ++k) {
      stg[t * 8 + k] = run;
      lst[t * 8 + k] = run;  // own cells only: no race
      run += v[k];
    }
  }
  if (t == 0) stg[NCELL] = NPTS;  // sentinel: end of last cell
  __syncthreads();

  // scatter (LDS cursors)
  float4* psb = psort + (size_t)b * NPTS;
#pragma unroll
  for (int k = 0; k < 8; ++k) {
    if (pc[k] >= 0) {
      const int pos = atomicAdd(&lst[pc[k]], 1);
      psb[pos] = make_float4(px[k], py[k], pz[k], __int_as_float(t + k * 1024));
    }
  }
}

// Candidate accumulation into per-lane top-2 of (max(d2,0), j) lexicographic
// -- exactly the reference's sort key: sqrt(max(d2,0)) monotone, stable
// top_k tie-break by lower index.
#define SCAN_RANGE(P0, P1)                                        \
  for (int p = (P0); p < (P1); ++p) {                             \
    const float4 P = ps[p];                                       \
    const float dot = xi * P.x + yi * P.y + zi * P.z;             \
    const float sqj = P.x * P.x + P.y * P.y + P.z * P.z;          \
    const float d2 = fmaxf((sqi + sqj) - 2.0f * dot, 0.0f);       \
    const int j = __float_as_int(P.w);                            \
    const bool lt0 = (d2 < b0) || (d2 == b0 && j < j0);           \
    const bool lt1 = (d2 < b1) || (d2 == b1 && j < j1);           \
    if (lt0) { b1 = b0; j1 = j0; b0 = d2; j0 = j; }               \
    else if (lt1) { b1 = d2; j1 = j; }                            \
  }

// Butterfly-merge step of two disjoint-set top-2 states (operates on mb*/mj*).
#define MERGE_XOR(MASK)                                                     \
  {                                                                         \
    const float ob0 = __shfl_xor(mb0, MASK);                                \
    const int oj0 = __shfl_xor(mj0, MASK);                                  \
    const float ob1 = __shfl_xor(mb1, MASK);                                \
    const int oj1 = __shfl_xor(mj1, MASK);                                  \
    const bool afirst = (mb0 < ob0) || (mb0 == ob0 && mj0 < oj0);           \
    const float w1 = afirst ? mb1 : ob1;                                    \
    const int wj1 = afirst ? mj1 : oj1;                                     \
    const float l0 = afirst ? ob0 : mb0;                                    \
    const int lj0 = afirst ? oj0 : mj0;                                     \
    mb0 = afirst ? mb0 : ob0;                                               \
    mj0 = afirst ? mj0 : oj0;                                               \
    const bool cs = (w1 < l0) || (w1 == l0 && wj1 < lj0);                   \
    mb1 = cs ? w1 : l0;                                                     \
    mj1 = cs ? wj1 : lj0;                                                   \
  }

// Fused NN search + gather/mean. 256 threads = 16 sorted-order queries x
// 16 candidate-split lanes (500 blocks/batch). starts[] read straight from
// L2 (32KB/batch, hot). Full r<=2 box (25 rows x 5 cells, ~125 pts at
// GDIM=20) as row-ranges; conservative (2h)^2 stop bound keeps the shell
// fallback ~1e-3 rare. Epilogue: 4 waves x 4 queries, unrolled gather.
__global__ __launch_bounds__(256, 8) void search_gather_kernel(
    const float4* __restrict__ psort, const int* __restrict__ starts,
    const float* __restrict__ preds, float* __restrict__ out) {
  __shared__ int snbr[16][3];  // j0, j1, qorig
  const int t = threadIdx.x;
  const int b = blockIdx.y;
  const int* stg = starts + b * STRIDE_ST;

  const int ql = t >> 4;  // 0..15
  const int s = t & 15;   // candidate split lane
  const int i = blockIdx.x * 16 + ql;  // 500*16 == 8000 exact
  const float4* ps = psort + (size_t)b * NPTS;
  const float4 Q = ps[i];
  const float xi = Q.x, yi = Q.y, zi = Q.z;
  const int qorig = __float_as_int(Q.w);
  const float sqi = xi * xi + yi * yi + zi * zi;  // same expr as reference
  const int cx = cell_clamp(xi), cy = cell_clamp(yi), cz = cell_clamp(zi);
  const int x0c = cx > 1 ? cx - 2 : 0;
  const int x1c = cx < GDIM - 2 ? cx + 2 : GDIM - 1;

  float b0 = INFINITY, b1 = INFINITY;
  int j0 = -1, j1 = -1;

  // ---- r<=2 box: 25 rows, lane s takes rows s and s+16 ----
  int rs[2], re[2];
#pragma unroll
  for (int rr = 0; rr < 2; ++rr) {
    const int kk = s + rr * 16;
    int lo = 0, hi = 0;
    if (kk < 25) {
      const int z = cz + kk / 5 - 2;
      const int y = cy + kk % 5 - 2;
      if ((unsigned)z < GDIM && (unsigned)y < GDIM) {
        const int rowbase = (z * GDIM + y) * GDIM;
        lo = stg[rowbase + x0c];
        hi = stg[rowbase + x1c + 1];  // sentinel covers rowbase+x1c+1 == NCELL
      }
    }
    rs[rr] = lo;
    re[rr] = hi;
  }
#pragma unroll
  for (int rr = 0; rr < 2; ++rr) { SCAN_RANGE(rs[rr], re[rr]) }

  // merged stop-check copy (per-lane b0..j1 stay disjoint-set accumulators)
  float mb0 = b0, mb1 = b1;
  int mj0 = j0, mj1 = j1;
  MERGE_XOR(1) MERGE_XOR(2) MERGE_XOR(4) MERGE_XOR(8)

  if (!(mb1 + EPS <= (2.0f * CELLH) * (2.0f * CELLH))) {
    // ---- rare fallback: expanding Chebyshev shells r>=3, row-range form ----
    for (int r = 3; r <= GDIM; ++r) {
      const int W = 2 * r + 1;
      for (int idx = s; idx < W * W; idx += 16) {
        const int dz = idx / W - r;
        const int dy = idx % W - r;
        const int z = cz + dz, y = cy + dy;
        if ((unsigned)z >= GDIM || (unsigned)y >= GDIM) continue;
        const int rowbase = (z * GDIM + y) * GDIM;
        if (dz == -r || dz == r || dy == -r || dy == r) {
          const int xl = cx > r ? cx - r : 0;
          const int xh = cx < GDIM - 1 - r ? cx + r : GDIM - 1;
          const int lo = stg[rowbase + xl], hi = stg[rowbase + xh + 1];
          SCAN_RANGE(lo, hi)
        } else {
          if (cx - r >= 0) {
            const int lo = stg[rowbase + cx - r], hi = stg[rowbase + cx - r + 1];
            SCAN_RANGE(lo, hi)
          }
          if (cx + r <= GDIM - 1) {
            const int lo = stg[rowbase + cx + r], hi = stg[rowbase + cx + r + 1];
            SCAN_RANGE(lo, hi)
          }
        }
      }
      mb0 = b0; mb1 = b1; mj0 = j0; mj1 = j1;
      MERGE_XOR(1) MERGE_XOR(2) MERGE_XOR(4) MERGE_XOR(8)
      const float rb = (float)r * CELLH;
      if (mb1 + EPS <= rb * rb) break;
    }
  }

  if (s == 0) {
    snbr[ql][0] = mj0;
    snbr[ql][1] = mj1;
    snbr[ql][2] = qorig;
  }
  __syncthreads();

  // ---- gather + mean epilogue: wave w handles queries 4w..4w+3 ----
  const int wave = t >> 6;
  const int lane = t & 63;
  const float* predb = preds + (size_t)b * NPTS * NCH;
  float* outb = out + (size_t)b * NPTS * NCH;
#pragma unroll
  for (int k = 0; k < 4; ++k) {
    const int q = wave * 4 + k;
    const int a = snbr[q][0];
    const int c = snbr[q][1];
    const int qo = snbr[q][2];
    const float4 va = ((const float4*)(predb + (size_t)a * NCH))[lane];
    const float4 vc = ((const float4*)(predb + (size_t)c * NCH))[lane];
    float4 r;
    r.x = 0.5f * (va.x + vc.x);
    r.y = 0.5f * (va.y + vc.y);
    r.z = 0.5f * (va.z + vc.z);
    r.w = 0.5f * (va.w + vc.w);
    ((float4*)(outb + (size_t)qo * NCH))[lane] = r;
  }
}

extern "C" void kernel_launch(void* const* d_in, const int* in_sizes, int n_in,
                              void* d_out, int out_size, void* d_ws, size_t ws_size,
                              hipStream_t stream) {
  const float* points = (const float*)d_in[0];
  const float* preds = (const float*)d_in[1];
  // d_in[2] (k_vector) unused: reference hardcodes k = 2.
  float* out = (float*)d_out;

  char* ws = (char*)d_ws;
  int* starts = (int*)(ws + WS_STARTS);
  float4* psort = (float4*)(ws + WS_PSORT);

  build_kernel<<<BATCH, 1024, 0, stream>>>(points, starts, psort);
  search_gather_kernel<<<dim3(NPTS / 16, BATCH), 256, 0, stream>>>(psort, starts, preds, out);
}